// Round 4
// baseline (1163.988 us; speedup 1.0000x reference)
//
#include <hip/hip_runtime.h>
#include <math.h>

#define NB 4
#define T 65536
#define TIN 8192
#define LL 256
#define KCL 6144   // per-layer kernel channels = 32*64*3

__device__ __forceinline__ float lrelu_f(float v) { return v >= 0.f ? v : 0.2f * v; }

// ---------------- prep1: weight transposes ----------------
// trb  [conv 6][c*3+k 192][oc 64]   from rb_w1/rb_w2 [i][oc][c][k]
// tbw  [J 192][o 256]               from bias_w [o][J]
// tkpin[(cin*5+k) 500][oc 64]       from kp_in_w [oc][cin][k]
// tlvc [layer 4][c*3+k 96][oc 32]   from lvc_w [layer][oc][c][k]
__global__ void __launch_bounds__(256) prep1(
    const float* __restrict__ bias_w, const float* __restrict__ rb_w1,
    const float* __restrict__ rb_w2, const float* __restrict__ kp_in_w,
    const float* __restrict__ lvc_w,
    float* __restrict__ tbw, float* __restrict__ trb, float* __restrict__ tkpin,
    float* __restrict__ tlvc) {
  __shared__ float t[64][193];
  const int bid = blockIdx.x, tid = threadIdx.x;
  if (bid < 10) {
    const float* src; float* dst; int dstride, dcol;
    if (bid < 6) {
      int i = bid >> 1, which = bid & 1;
      src = (which ? rb_w2 : rb_w1) + (size_t)i * 12288;
      dst = trb + (size_t)bid * 12288; dstride = 64; dcol = 0;
    } else {
      int ob = bid - 6;
      src = bias_w + (size_t)ob * 64 * 192;
      dst = tbw; dstride = 256; dcol = ob * 64;
    }
    for (int idx = tid; idx < 64 * 192; idx += 256) {
      int o = idx / 192, J = idx % 192;
      t[o][J] = src[(size_t)o * 192 + J];
    }
    __syncthreads();
    for (int idx = tid; idx < 64 * 192; idx += 256) {
      int J = idx >> 6, o = idx & 63;
      dst[(size_t)J * dstride + dcol + o] = t[o][J];
    }
  } else if (bid == 10) {
    for (int idx = tid; idx < 500 * 64; idx += 256) {
      int row = idx >> 6, o = idx & 63;
      tkpin[idx] = kp_in_w[o * 500 + row];
    }
  } else {
    for (int idx = tid; idx < 12288; idx += 256) {
      int layer = idx / 3072, r = idx % 3072, ck = r >> 5, o = r & 31;
      tlvc[idx] = lvc_w[(size_t)layer * 3072 + o * 96 + ck];
    }
  }
}

// per-layer kern_w transpose: tkwL[g 96][J 192][o 64]
__global__ void __launch_bounds__(256) prep_kern(const float* __restrict__ kern_w,
                                                 float* __restrict__ tkwL, int layer) {
  __shared__ float t[64][193];
  const int g = blockIdx.x, tid = threadIdx.x;
  const int ci = g / 3, kk = g % 3;
  const float* src = kern_w + ((size_t)layer * KCL + ci * 192 + kk) * 192;
  float* dst = tkwL + (size_t)g * 12288;
  for (int idx = tid; idx < 64 * 192; idx += 256) {
    int o = idx / 192, J = idx % 192;
    t[o][J] = src[(size_t)o * 576 + J];
  }
  __syncthreads();
  for (int idx = tid; idx < 64 * 192; idx += 256) {
    int J = idx >> 6, o = idx & 63;
    dst[(size_t)J * 64 + o] = t[o][J];
  }
}

// ---------------- phase1: trunk (32 blocks, 8 units each) + convt (264 blocks) ----------------
union Phase1LDS {
  struct { float xs[32][264]; float wm[64][128]; } cvt;   // 66.6 KB
  struct { float hs[8][64][20]; float xsp[100][52]; } trk; // 61.8 KB
};

__global__ void __launch_bounds__(512) phase1(
    const float* __restrict__ x, const float* __restrict__ cw,
    const float* __restrict__ cbias, float* __restrict__ hout,
    const float* __restrict__ spec,
    const float* __restrict__ tkpin, const float* __restrict__ kp_in_b,
    const float* __restrict__ trb, const float* __restrict__ rb_b1,
    const float* __restrict__ rb_b2, float* __restrict__ kp_h) {
  __shared__ Phase1LDS sm;
  const int bid = blockIdx.x;
  const int tid = threadIdx.x;
  const int lane = tid & 63, wv = tid >> 6;

  if (bid < 32) {
    // ================= trunk role: 8 single-wave units, 2 waves/SIMD =================
    const int b = bid >> 3;             // batch
    const int lb = (bid & 7) * 32;      // block l-base (32 cols)
    const int l0 = lb + wv * 4;         // unit's 4 output cols
    const int og = lane >> 1;           // 0..31 oc-pair
    const int colg = lane & 1;          // 0..1 -> 8 halo cols each
    const int colg8 = colg * 8;
    const int obase = og * 2;
    float (*hsu)[20] = sm.trk.hs[wv];

    // zero-init hs + stage shared spec window (labs = lb-8+cx, cx<52)
    for (int i = tid; i < 8 * 64 * 20; i += 512) ((float*)sm.trk.hs)[i] = 0.f;
    for (int i = tid; i < 100 * 52; i += 512) {
      int cin = i / 52, cx = i - cin * 52;
      int labs = lb - 8 + cx;
      float v = (labs >= 0 && labs < 256)
                    ? spec[((size_t)b * 100 + cin) * LL + labs] : 0.f;
      sm.trk.xsp[cin][cx] = v;
    }
    __syncthreads();

    // ---- kp_in (k=5, pad 2): compute rel 0..15 (labs = l0-6+rel) ----
    float hcur[2][8];
    {
      float acc[2][8];
      float2 bb = *(const float2*)(kp_in_b + obase);
#pragma unroll
      for (int q = 0; q < 8; ++q) { acc[0][q] = bb.x; acc[1][q] = bb.y; }
#pragma unroll 2
      for (int cin = 0; cin < 100; ++cin) {
        const float* xrow = &sm.trk.xsp[cin][wv * 4 + colg8];
        float x12[12];
        *(float4*)&x12[0] = *(const float4*)(xrow);
        *(float4*)&x12[4] = *(const float4*)(xrow + 4);
        *(float4*)&x12[8] = *(const float4*)(xrow + 8);
        const float* wp = tkpin + (size_t)(cin * 5) * 64 + obase;
#pragma unroll
        for (int k = 0; k < 5; ++k) {
          float2 w = *(const float2*)(wp + k * 64);
#pragma unroll
          for (int q = 0; q < 8; ++q) {
            acc[0][q] += x12[q + k] * w.x;
            acc[1][q] += x12[q + k] * w.y;
          }
        }
      }
#pragma unroll
      for (int oi = 0; oi < 2; ++oi)
#pragma unroll
        for (int q = 0; q < 8; ++q) {
          int rel = colg8 + q, labs = l0 - 6 + rel;
          float v = (labs >= 0 && labs < 256) ? acc[oi][q] : 0.f;
          hcur[oi][q] = v;
          hsu[obase + oi][rel + 1] = v;
        }
    }

    // ---- 6 convs (3 residual blocks); output valid rel in [cv+1, 15-cv) ----
    for (int cv = 0; cv < 6; ++cv) {
      const float* wb = trb + (size_t)cv * 12288;
      const float* bp = (cv & 1) ? rb_b2 + (cv >> 1) * 64 : rb_b1 + (cv >> 1) * 64;
      float2 bb = *(const float2*)(bp + obase);
      float acc[2][8];
#pragma unroll
      for (int q = 0; q < 8; ++q) { acc[0][q] = bb.x; acc[1][q] = bb.y; }
#pragma unroll 4
      for (int c = 0; c < 64; ++c) {
        float x10[10];
        *(float4*)&x10[0] = *(const float4*)&hsu[c][colg8];
        *(float4*)&x10[4] = *(const float4*)&hsu[c][colg8 + 4];
        *(float2*)&x10[8] = *(const float2*)&hsu[c][colg8 + 8];
        const float* wp = wb + (size_t)(c * 192) + obase;
        float2 w0 = *(const float2*)(wp);
        float2 w1 = *(const float2*)(wp + 64);
        float2 w2 = *(const float2*)(wp + 128);
#pragma unroll
        for (int q = 0; q < 8; ++q) {
          acc[0][q] += x10[q] * w0.x + x10[q + 1] * w1.x + x10[q + 2] * w2.x;
          acc[1][q] += x10[q] * w0.y + x10[q + 1] * w1.y + x10[q + 2] * w2.y;
        }
      }
      const int lo = cv + 1, hi = 15 - cv;
#pragma unroll
      for (int oi = 0; oi < 2; ++oi)
#pragma unroll
        for (int q = 0; q < 8; ++q) {
          int rel = colg8 + q, labs = l0 - 6 + rel;
          float v = lrelu_f(acc[oi][q]);
          if (cv & 1) v += hcur[oi][q];
          bool ok = (rel >= lo) && (rel < hi) && (labs >= 0) && (labs < 256);
          v = ok ? v : 0.f;
          if (cv & 1) hcur[oi][q] = v;
          if (cv < 5) hsu[obase + oi][rel + 1] = v;
        }
    }

    // ---- write kp_h: final valid rel in [6,10) -> labs l0..l0+3 ----
#pragma unroll
    for (int oi = 0; oi < 2; ++oi)
#pragma unroll
      for (int q = 0; q < 8; ++q) {
        int rel = colg8 + q;
        if (rel >= 6 && rel < 10)
          kp_h[((size_t)b * 64 + obase + oi) * LL + l0 + rel - 6] = hcur[oi][q];
      }
    return;
  }

  // ================= convt role (round-0, known good) =================
  const int cb = bid - 32;
  const int bx = cb % 33;
  const int rr = cb / 33;
  const int mtp = rr & 1;
  const int b = rr >> 1;
  const int s0base = bx * 256;
  float (*xs)[264] = sm.cvt.xs;
  float (*wm)[128] = sm.cvt.wm;

  const float* xb = x + (size_t)b * 32 * TIN;
  for (int idx = tid; idx < 32 * 64; idx += 512) {
    int c = idx >> 6, q = idx & 63;
    int p = s0base + q * 4;
    float4 v = (p + 3 < TIN) ? *(const float4*)(xb + c * TIN + p)
                             : make_float4(0.f, 0.f, 0.f, 0.f);
    *(float4*)&xs[c][4 + 4 * q] = v;
  }
  if (tid < 32) {
    int p = s0base - 1;
    xs[tid][3] = (p >= 0) ? xb[tid * TIN + p] : 0.f;
  }
  for (int idx = tid; idx < 8192; idx += 512) {
    int i = idx >> 7, mm = idx & 127;
    int oo = mtp * 16 + (mm >> 3), k0 = mm & 7;
    wm[i][mm] = (i < 32) ? cw[i * 512 + oo * 16 + k0]
                         : cw[(i - 32) * 512 + oo * 16 + k0 + 8];
  }
  __syncthreads();

  float acc[2][8][4];   // [ol][k0][si]
#pragma unroll
  for (int ol = 0; ol < 2; ++ol) {
    float bo = cbias[mtp * 16 + wv * 2 + ol];
#pragma unroll
    for (int k0 = 0; k0 < 8; ++k0)
#pragma unroll
      for (int si = 0; si < 4; ++si) acc[ol][k0][si] = bo;
  }

  for (int c = 0; c < 32; ++c) {
    float xm1[4], x0[4];
#pragma unroll
    for (int si = 0; si < 4; ++si) {
      xm1[si] = xs[c][lane + si * 64 + 3];
      x0[si]  = xs[c][lane + si * 64 + 4];
    }
    float w0[16], w1[16];
#pragma unroll
    for (int q = 0; q < 4; ++q) {
      *(float4*)&w0[q * 4] = *(const float4*)&wm[c][wv * 16 + q * 4];
      *(float4*)&w1[q * 4] = *(const float4*)&wm[32 + c][wv * 16 + q * 4];
    }
#pragma unroll
    for (int ol = 0; ol < 2; ++ol)
#pragma unroll
      for (int k0 = 0; k0 < 8; ++k0)
#pragma unroll
        for (int si = 0; si < 4; ++si)
          acc[ol][k0][si] += x0[si] * w0[ol * 8 + k0] + xm1[si] * w1[ol * 8 + k0];
  }

#pragma unroll
  for (int ol = 0; ol < 2; ++ol) {
    float* ob = hout + ((size_t)b * 32 + mtp * 16 + wv * 2 + ol) * T;
#pragma unroll
    for (int si = 0; si < 4; ++si) {
      int tb = (s0base + lane + si * 64) * 8 - 4;
      if (tb >= 0 && tb < T)
        *(float4*)(ob + tb) = make_float4(acc[ol][0][si], acc[ol][1][si],
                                          acc[ol][2][si], acc[ol][3][si]);
      if (tb + 4 >= 0 && tb + 4 < T)
        *(float4*)(ob + tb + 4) = make_float4(acc[ol][4][si], acc[ol][5][si],
                                              acc[ol][6][si], acc[ol][7][si]);
    }
  }
}

// ---------------- kern head GEMM: weights via per-lane VMEM from tkwL/tbw ----------------
__global__ void __launch_bounds__(256, 4) kern_head(const float* __restrict__ kp_h,
                                                    const float* __restrict__ tkwL,
                                                    const float* __restrict__ kb,
                                                    const float* __restrict__ tbw,
                                                    const float* __restrict__ bias_b,
                                                    float* __restrict__ kh,
                                                    float* __restrict__ bh, int layer) {
  const int bx = blockIdx.x, b = blockIdx.y;
  const bool isbias = (bx >= 192);
  const int tid = threadIdx.x, lane = tid & 63, wv = tid >> 6;
  __shared__ float xs[32][264];

  int g = 0, oc0 = 0, ci = 0, kk = 0, ocb0 = 0;
  const float* wbase;
  int wstride;
  if (!isbias) {
    g = bx >> 1; oc0 = (bx & 1) * 32;
    ci = g / 3; kk = g - ci * 3;
    wbase = tkwL + (size_t)g * 12288 + oc0 + wv * 8;
    wstride = 64;
  } else {
    ocb0 = (bx - 192) * 32;
    wbase = tbw + ocb0 + wv * 8;
    wstride = 256;
  }

  float acc[8][4];
#pragma unroll
  for (int oi = 0; oi < 8; ++oi) {
    float bv = isbias ? bias_b[ocb0 + wv * 8 + oi]
                      : kb[layer * KCL + (ci * 64 + oc0 + wv * 8 + oi) * 3 + kk];
#pragma unroll
    for (int si = 0; si < 4; ++si) acc[oi][si] = bv;
  }

  for (int half = 0; half < 2; ++half) {
    const int hc0 = half * 32;
    __syncthreads();
    for (int idx = tid; idx < 32 * 64; idx += 256) {
      int c = idx >> 6, q = idx & 63;
      *(float4*)&xs[c][4 + 4 * q] =
          *(const float4*)(kp_h + ((size_t)b * 64 + hc0 + c) * LL + 4 * q);
    }
    if (tid < 32) { xs[tid][3] = 0.f; xs[tid][260] = 0.f; }
    __syncthreads();
    const float* wb2 = wbase + (size_t)(hc0 * 3) * wstride;
    for (int c = 0; c < 32; ++c) {
#pragma unroll
      for (int t = 0; t < 3; ++t) {
        float w8[8];
        *(float4*)&w8[0] = *(const float4*)(wb2 + (size_t)(c * 3 + t) * wstride);
        *(float4*)&w8[4] = *(const float4*)(wb2 + (size_t)(c * 3 + t) * wstride + 4);
        float xv[4];
#pragma unroll
        for (int si = 0; si < 4; ++si) xv[si] = xs[c][lane + si * 64 + t + 3];
#pragma unroll
        for (int oi = 0; oi < 8; ++oi)
#pragma unroll
          for (int si = 0; si < 4; ++si)
            acc[oi][si] += w8[oi] * xv[si];
      }
    }
  }

  if (!isbias) {
#pragma unroll
    for (int si = 0; si < 4; ++si) {
      int l = lane + si * 64;
      float* op = kh + ((size_t)b * LL + l) * KCL + g * 64 + oc0 + wv * 8;
      *(float4*)(op)     = make_float4(acc[0][si], acc[1][si], acc[2][si], acc[3][si]);
      *(float4*)(op + 4) = make_float4(acc[4][si], acc[5][si], acc[6][si], acc[7][si]);
    }
  } else {
#pragma unroll
    for (int oi = 0; oi < 8; ++oi) {
      float* op = bh + ((size_t)b * 256 + ocb0 + wv * 8 + oi) * LL;
#pragma unroll
      for (int si = 0; si < 4; ++si)
        op[lane + si * 64] = acc[oi][si];
    }
  }
}

// ---------------- fused dilated conv + LVC + gate + residual ----------------
// weights (ks, ws) via per-lane VMEM global loads; LDS holds only xh (40.4 KB)
__global__ void __launch_bounds__(512, 4) layer_fused(
    const float* __restrict__ kh, const float* __restrict__ bh,
    const float* __restrict__ wT, const float* __restrict__ bias,
    const float* __restrict__ hin, float* __restrict__ hout,
    int layer, int dil) {
  const int l = blockIdx.x, b = blockIdx.y;
  const int tid = threadIdx.x, lane = tid & 63, wv = tid >> 6;
  const int t0 = l * 256;
  __shared__ float xh[32][316];   // 40.4 KB

  const float* hb = hin + (size_t)b * 32 * T;
  for (int idx = tid; idx < 32 * 64; idx += 512) {
    int c = idx >> 6, q = idx & 63;
    float4 v = *(const float4*)(hb + (size_t)c * T + t0 + 4 * q);
    *(float4*)&xh[c][32 + 4 * q] = make_float4(lrelu_f(v.x), lrelu_f(v.y),
                                               lrelu_f(v.z), lrelu_f(v.w));
  }
  for (int idx = tid; idx < 32 * 60; idx += 512) {
    int c = idx / 60, r = idx - c * 60;
    int jj = (r < 32) ? r : (256 + r);
    int t = t0 + jj - 32;
    xh[c][jj] = (t >= 0 && t < T) ? lrelu_f(hb[(size_t)c * T + t]) : 0.f;
  }
  __syncthreads();

  // Phase B: dilated conv. wave owns oc8b = (wv&3)*8; col = lane + (si*2+hw)*64, 3 si.
  const int oc8b = (wv & 3) * 8;
  const int hw = wv >> 2;
  float yv[3][8];
  {
    float a[3][8];
    float bv8[8];
    *(float4*)&bv8[0] = *(const float4*)(bias + oc8b);
    *(float4*)&bv8[4] = *(const float4*)(bias + oc8b + 4);
#pragma unroll
    for (int si = 0; si < 3; ++si)
#pragma unroll
      for (int oi = 0; oi < 8; ++oi) a[si][oi] = bv8[oi];
    for (int c = 0; c < 32; ++c) {
#pragma unroll
      for (int k = 0; k < 3; ++k) {
        const float* wp = wT + (size_t)(c * 3 + k) * 32 + oc8b;
        float w8[8];
        *(float4*)&w8[0] = *(const float4*)(wp);
        *(float4*)&w8[4] = *(const float4*)(wp + 4);
        float xv[3];
#pragma unroll
        for (int si = 0; si < 3; ++si) {
          int col = lane + (si * 2 + hw) * 64;
          int colc = (col < 258) ? col : 257;
          xv[si] = xh[c][colc + 31 + (k - 1) * dil];
        }
#pragma unroll
        for (int si = 0; si < 3; ++si)
#pragma unroll
          for (int oi = 0; oi < 8; ++oi)
            a[si][oi] += xv[si] * w8[oi];
      }
    }
#pragma unroll
    for (int si = 0; si < 3; ++si) {
      int col = lane + (si * 2 + hw) * 64;
      int t = t0 - 1 + col;
      bool tval = (t >= 0 && t < T) && (col < 258);
#pragma unroll
      for (int oi = 0; oi < 8; ++oi)
        yv[si][oi] = tval ? lrelu_f(a[si][oi]) : 0.f;
    }
  }
  __syncthreads();

  // Phase C: write y into xh central region
#pragma unroll
  for (int si = 0; si < 3; ++si) {
    int col = lane + (si * 2 + hw) * 64;
    if (col < 258) {
#pragma unroll
      for (int oi = 0; oi < 8; ++oi) xh[oc8b + oi][col + 31] = yv[si][oi];
    }
  }
  __syncthreads();

  // Phase D: LVC — kernels direct from kh (VMEM), x from LDS
  const int oc8 = (wv & 3) * 8;
  const int sh  = wv >> 2;
  const float* krb = kh + ((size_t)b * LL + l) * KCL;
  float acc_a[8][2], acc_g[8][2];
#pragma unroll
  for (int oi = 0; oi < 8; ++oi) {
    float ba = bh[((size_t)b * 256 + layer * 64 + oc8 + oi) * LL + l];
    float bg = bh[((size_t)b * 256 + layer * 64 + 32 + oc8 + oi) * LL + l];
#pragma unroll
    for (int si = 0; si < 2; ++si) { acc_a[oi][si] = ba; acc_g[oi][si] = bg; }
  }

  for (int c = 0; c < 32; ++c) {
#pragma unroll
    for (int k = 0; k < 3; ++k) {
      const float* kr = krb + (size_t)(c * 3 + k) * 64;
      float wa[8], wg[8];
      *(float4*)&wa[0] = *(const float4*)(kr + oc8);
      *(float4*)&wa[4] = *(const float4*)(kr + oc8 + 4);
      *(float4*)&wg[0] = *(const float4*)(kr + 32 + oc8);
      *(float4*)&wg[4] = *(const float4*)(kr + 32 + oc8 + 4);
      float xv2[2];
#pragma unroll
      for (int si = 0; si < 2; ++si) {
        int s = lane + (sh * 2 + si) * 64;
        xv2[si] = xh[c][s + k + 31];
      }
#pragma unroll
      for (int oi = 0; oi < 8; ++oi)
#pragma unroll
        for (int si = 0; si < 2; ++si) {
          acc_a[oi][si] += wa[oi] * xv2[si];
          acc_g[oi][si] += wg[oi] * xv2[si];
        }
    }
  }

  // Phase E: gate + residual
#pragma unroll
  for (int oi = 0; oi < 8; ++oi) {
    const float* hip = hin + ((size_t)b * 32 + oc8 + oi) * T + t0;
    float* hop = hout + ((size_t)b * 32 + oc8 + oi) * T + t0;
#pragma unroll
    for (int si = 0; si < 2; ++si) {
      int s = lane + (sh * 2 + si) * 64;
      float a = acc_a[oi][si], g = acc_g[oi][si];
      float sg = 1.f / (1.f + __expf(-a));
      float th = tanhf(g);
      hop[s] = sg * th + hip[s];
    }
  }
}

extern "C" void kernel_launch(void* const* d_in, const int* in_sizes, int n_in,
                              void* d_out, int out_size, void* d_ws, size_t ws_size,
                              hipStream_t stream) {
  const float* hidden  = (const float*)d_in[0];
  const float* spec    = (const float*)d_in[1];
  const float* convt_w = (const float*)d_in[2];
  const float* convt_b = (const float*)d_in[3];
  const float* kp_in_w = (const float*)d_in[4];
  const float* kp_in_b = (const float*)d_in[5];
  const float* rb_w1   = (const float*)d_in[6];
  const float* rb_b1   = (const float*)d_in[7];
  const float* rb_w2   = (const float*)d_in[8];
  const float* rb_b2   = (const float*)d_in[9];
  const float* kern_w  = (const float*)d_in[10];
  const float* kern_b  = (const float*)d_in[11];
  const float* bias_w  = (const float*)d_in[12];
  const float* bias_b  = (const float*)d_in[13];
  const float* lvc_w   = (const float*)d_in[14];
  const float* lvc_b   = (const float*)d_in[15];

  float* wsp = (float*)d_ws;
  float* h_ws     = wsp;                                 // NB*32*T        = 8,388,608
  float* kh_layer = h_ws + (size_t)NB * 32 * T;          // NB*LL*KCL      = 6,291,456
  float* bh       = kh_layer + (size_t)NB * LL * KCL;    // NB*256*LL      =   262,144
  float* kp_h     = bh + (size_t)NB * 256 * LL;          // NB*64*LL       =    65,536
  float* tkwL     = kp_h + (size_t)NB * 64 * LL;         // 96*192*64      = 1,179,648
  float* tbw      = tkwL + (size_t)96 * 192 * 64;        // 192*256        =    49,152
  float* trb      = tbw + (size_t)192 * 256;             // 6*192*64       =    73,728
  float* tkpin    = trb + (size_t)6 * 192 * 64;          // 500*64         =    32,000
  float* tlvc     = tkpin + (size_t)500 * 64;            // 4*96*32        =    12,288

  float* h0 = (float*)d_out;
  float* h1 = h_ws;

  // 0) one-time weight transposes
  prep1<<<dim3(12), 256, 0, stream>>>(bias_w, rb_w1, rb_w2, kp_in_w, lvc_w,
                                      tbw, trb, tkpin, tlvc);

  // 1) merged trunk (blocks 0..31) + convt (blocks 32..295)
  phase1<<<dim3(296), 512, 0, stream>>>(hidden, convt_w, convt_b, h0,
                                        spec, tkpin, kp_in_b,
                                        trb, rb_b1, rb_b2, kp_h);

  static const int dil[4] = {1, 3, 9, 27};
  float* hin = h0;
  float* hout = h1;
  for (int layer = 0; layer < 4; ++layer) {
    prep_kern<<<dim3(96), 256, 0, stream>>>(kern_w, tkwL, layer);
    kern_head<<<dim3(layer == 0 ? 200 : 192, NB), 256, 0, stream>>>(
        kp_h, tkwL, kern_b, tbw, bias_b, kh_layer, bh, layer);
    layer_fused<<<dim3(LL, NB), 512, 0, stream>>>(
        kh_layer, bh, tlvc + (size_t)layer * 3072, lvc_b + layer * 32,
        hin, hout, layer, dil[layer]);
    float* tmp = hin; hin = hout; hout = tmp;
  }
  // after 4 swaps the final output landed in h0 = d_out
}

// Round 7
// 807.407 us; speedup vs baseline: 1.4416x; 1.4416x over previous
//
#include <hip/hip_runtime.h>
#include <math.h>

#define NB 4
#define T 65536
#define TIN 8192
#define LL 256
#define KCL 6144   // per-layer kernel channels = 32*64*3

__device__ __forceinline__ float lrelu_f(float v) { return v >= 0.f ? v : 0.2f * v; }

// ---------------- prep1: weight transposes for trunk's divergent per-lane loads ----------------
// trb  [conv 6][c*3+k 192][oc 64]   from rb_w1/rb_w2 [i][oc][c][k]
// tkpin[(cin*5+k) 500][oc 64]       from kp_in_w [oc][cin][k]
__global__ void __launch_bounds__(256) prep1(
    const float* __restrict__ rb_w1, const float* __restrict__ rb_w2,
    const float* __restrict__ kp_in_w,
    float* __restrict__ trb, float* __restrict__ tkpin) {
  __shared__ float t[64][193];
  const int bid = blockIdx.x, tid = threadIdx.x;
  if (bid < 6) {
    int i = bid >> 1, which = bid & 1;
    const float* src = (which ? rb_w2 : rb_w1) + (size_t)i * 12288;
    float* dst = trb + (size_t)bid * 12288;
    for (int idx = tid; idx < 64 * 192; idx += 256) {
      int o = idx / 192, J = idx % 192;
      t[o][J] = src[(size_t)o * 192 + J];
    }
    __syncthreads();
    for (int idx = tid; idx < 64 * 192; idx += 256) {
      int J = idx >> 6, o = idx & 63;
      dst[(size_t)J * 64 + o] = t[o][J];
    }
  } else {
    for (int idx = tid; idx < 500 * 64; idx += 256) {
      int row = idx >> 6, o = idx & 63;
      tkpin[idx] = kp_in_w[o * 500 + row];
    }
  }
}

// ---------------- phase1: trunk (128 blocks, 2 units each, first) + convt (264 blocks) ----------------
// trunk: 256 independent single-wave units spread over 128 blocks so they
// co-reside with convt blocks across ~all CUs (2 blocks/CU by LDS).
union Phase1LDS {
  struct { float xs[32][264]; float wm[64][128]; } cvt;       // 66.6 KB
  struct { float hs[2][64][20]; float xsp[2][100][24]; } trk; // 29.4 KB
};

__global__ void __launch_bounds__(512) phase1(
    const float* __restrict__ x, const float* __restrict__ cw,
    const float* __restrict__ cbias, float* __restrict__ hout,
    const float* __restrict__ spec,
    const float* __restrict__ tkpin, const float* __restrict__ kp_in_b,
    const float* __restrict__ trb, const float* __restrict__ rb_b1,
    const float* __restrict__ rb_b2, float* __restrict__ kp_h) {
  __shared__ Phase1LDS sm;
  const int bid = blockIdx.x;
  const int tid = threadIdx.x;
  const int lane = tid & 63, wv = tid >> 6;

  if (bid < 128) {
    // ================= trunk role: 2 single-wave units per block =================
    if (wv >= 2) return;
    const int unit = bid * 2 + wv;       // 0..255
    const int b = unit >> 6;             // batch
    const int chunk = unit & 63;         // 64 chunks x 4 cols = 256 cols
    const int l0 = chunk * 4;
    const int og = lane >> 1;            // 0..31 oc-pair
    const int colg = lane & 1;           // 0..1  -> 8 halo cols each
    const int colg8 = colg * 8;
    const int obase = og * 2;
    float (*hsu)[20] = sm.trk.hs[wv];
    float (*xspu)[24] = sm.trk.xsp[wv];

    // zero-init hs (idx 0 and 17..19 stay 0 = halo padding)
    for (int i = lane; i < 64 * 20; i += 64) ((float*)hsu)[i] = 0.f;

    // stage ALL spec channels: xsp[cin][cx], cx = labs-(l0-8), window 20 (+4 pad)
    for (int i = lane; i < 100 * 24; i += 64) {
      int cin = i / 24, cx = i - cin * 24;
      float v = 0.f;
      if (cx < 20) {
        int labs = l0 - 8 + cx;
        if (labs >= 0 && labs < 256)
          v = spec[((size_t)b * 100 + cin) * LL + labs];
      }
      xspu[cin][cx] = v;
    }

    // ---- kp_in (k=5, pad 2): compute rel 0..15 (labs = l0-6+rel) ----
    float hcur[2][8];
    {
      float acc[2][8];
      float2 bb = *(const float2*)(kp_in_b + obase);
#pragma unroll
      for (int q = 0; q < 8; ++q) { acc[0][q] = bb.x; acc[1][q] = bb.y; }
#pragma unroll 2
      for (int cin = 0; cin < 100; ++cin) {
        float x12[12];
        *(float4*)&x12[0] = *(const float4*)&xspu[cin][colg8];
        *(float4*)&x12[4] = *(const float4*)&xspu[cin][colg8 + 4];
        *(float4*)&x12[8] = *(const float4*)&xspu[cin][colg8 + 8];
        const float* wp = tkpin + (size_t)(cin * 5) * 64 + obase;
#pragma unroll
        for (int k = 0; k < 5; ++k) {
          float2 w = *(const float2*)(wp + k * 64);
#pragma unroll
          for (int q = 0; q < 8; ++q) {
            acc[0][q] += x12[q + k] * w.x;
            acc[1][q] += x12[q + k] * w.y;
          }
        }
      }
#pragma unroll
      for (int oi = 0; oi < 2; ++oi)
#pragma unroll
        for (int q = 0; q < 8; ++q) {
          int rel = colg8 + q, labs = l0 - 6 + rel;
          float v = (labs >= 0 && labs < 256) ? acc[oi][q] : 0.f;
          hcur[oi][q] = v;
          hsu[obase + oi][rel + 1] = v;
        }
    }

    // ---- 6 convs (3 residual blocks); output valid rel in [cv+1, 15-cv) ----
    for (int cv = 0; cv < 6; ++cv) {
      const float* wb = trb + (size_t)cv * 12288;
      const float* bp = (cv & 1) ? rb_b2 + (cv >> 1) * 64 : rb_b1 + (cv >> 1) * 64;
      float2 bb = *(const float2*)(bp + obase);
      float acc[2][8];
#pragma unroll
      for (int q = 0; q < 8; ++q) { acc[0][q] = bb.x; acc[1][q] = bb.y; }
#pragma unroll 4
      for (int c = 0; c < 64; ++c) {
        float x10[10];
        *(float4*)&x10[0] = *(const float4*)&hsu[c][colg8];
        *(float4*)&x10[4] = *(const float4*)&hsu[c][colg8 + 4];
        *(float2*)&x10[8] = *(const float2*)&hsu[c][colg8 + 8];
        const float* wp = wb + (size_t)(c * 192) + obase;
        float2 w0 = *(const float2*)(wp);
        float2 w1 = *(const float2*)(wp + 64);
        float2 w2 = *(const float2*)(wp + 128);
#pragma unroll
        for (int q = 0; q < 8; ++q) {
          acc[0][q] += x10[q] * w0.x + x10[q + 1] * w1.x + x10[q + 2] * w2.x;
          acc[1][q] += x10[q] * w0.y + x10[q + 1] * w1.y + x10[q + 2] * w2.y;
        }
      }
      const int lo = cv + 1, hi = 15 - cv;
#pragma unroll
      for (int oi = 0; oi < 2; ++oi)
#pragma unroll
        for (int q = 0; q < 8; ++q) {
          int rel = colg8 + q, labs = l0 - 6 + rel;
          float v = lrelu_f(acc[oi][q]);
          if (cv & 1) v += hcur[oi][q];
          bool ok = (rel >= lo) && (rel < hi) && (labs >= 0) && (labs < 256);
          v = ok ? v : 0.f;
          if (cv & 1) hcur[oi][q] = v;
          if (cv < 5) hsu[obase + oi][rel + 1] = v;
        }
    }

    // ---- write kp_h: final valid rel in [6,10) -> labs l0..l0+3 ----
#pragma unroll
    for (int oi = 0; oi < 2; ++oi)
#pragma unroll
      for (int q = 0; q < 8; ++q) {
        int rel = colg8 + q;
        if (rel >= 6 && rel < 10)
          kp_h[((size_t)b * 64 + obase + oi) * LL + l0 + rel - 6] = hcur[oi][q];
      }
    return;
  }

  // ================= convt role (round-0, known good) =================
  const int cb = bid - 128;
  const int bx = cb % 33;
  const int rr = cb / 33;
  const int mtp = rr & 1;
  const int b = rr >> 1;
  const int s0base = bx * 256;
  float (*xs)[264] = sm.cvt.xs;
  float (*wm)[128] = sm.cvt.wm;

  const float* xb = x + (size_t)b * 32 * TIN;
  for (int idx = tid; idx < 32 * 64; idx += 512) {
    int c = idx >> 6, q = idx & 63;
    int p = s0base + q * 4;
    float4 v = (p + 3 < TIN) ? *(const float4*)(xb + c * TIN + p)
                             : make_float4(0.f, 0.f, 0.f, 0.f);
    *(float4*)&xs[c][4 + 4 * q] = v;
  }
  if (tid < 32) {
    int p = s0base - 1;
    xs[tid][3] = (p >= 0) ? xb[tid * TIN + p] : 0.f;
  }
  for (int idx = tid; idx < 8192; idx += 512) {
    int i = idx >> 7, mm = idx & 127;
    int oo = mtp * 16 + (mm >> 3), k0 = mm & 7;
    wm[i][mm] = (i < 32) ? cw[i * 512 + oo * 16 + k0]
                         : cw[(i - 32) * 512 + oo * 16 + k0 + 8];
  }
  __syncthreads();

  float acc[2][8][4];   // [ol][k0][si]
#pragma unroll
  for (int ol = 0; ol < 2; ++ol) {
    float bo = cbias[mtp * 16 + wv * 2 + ol];
#pragma unroll
    for (int k0 = 0; k0 < 8; ++k0)
#pragma unroll
      for (int si = 0; si < 4; ++si) acc[ol][k0][si] = bo;
  }

  for (int c = 0; c < 32; ++c) {
    float xm1[4], x0[4];
#pragma unroll
    for (int si = 0; si < 4; ++si) {
      xm1[si] = xs[c][lane + si * 64 + 3];
      x0[si]  = xs[c][lane + si * 64 + 4];
    }
    float w0[16], w1[16];
#pragma unroll
    for (int q = 0; q < 4; ++q) {
      *(float4*)&w0[q * 4] = *(const float4*)&wm[c][wv * 16 + q * 4];
      *(float4*)&w1[q * 4] = *(const float4*)&wm[32 + c][wv * 16 + q * 4];
    }
#pragma unroll
    for (int ol = 0; ol < 2; ++ol)
#pragma unroll
      for (int k0 = 0; k0 < 8; ++k0)
#pragma unroll
        for (int si = 0; si < 4; ++si)
          acc[ol][k0][si] += x0[si] * w0[ol * 8 + k0] + xm1[si] * w1[ol * 8 + k0];
  }

#pragma unroll
  for (int ol = 0; ol < 2; ++ol) {
    float* ob = hout + ((size_t)b * 32 + mtp * 16 + wv * 2 + ol) * T;
#pragma unroll
    for (int si = 0; si < 4; ++si) {
      int tb = (s0base + lane + si * 64) * 8 - 4;
      if (tb >= 0 && tb < T)
        *(float4*)(ob + tb) = make_float4(acc[ol][0][si], acc[ol][1][si],
                                          acc[ol][2][si], acc[ol][3][si]);
      if (tb + 4 >= 0 && tb + 4 < T)
        *(float4*)(ob + tb + 4) = make_float4(acc[ol][4][si], acc[ol][5][si],
                                              acc[ol][6][si], acc[ol][7][si]);
    }
  }
}

// ---------------- kern head GEMM (round-0, known good) ----------------
__global__ void __launch_bounds__(256, 3) kern_head(const float* __restrict__ kp_h,
                                                    const float* __restrict__ kw,
                                                    const float* __restrict__ kb,
                                                    const float* __restrict__ bias_w,
                                                    const float* __restrict__ bias_b,
                                                    float* __restrict__ kh,
                                                    float* __restrict__ bh, int layer) {
    const int bx = blockIdx.x, b = blockIdx.y;
    const bool isbias = (bx >= 192);
    const int tid = threadIdx.x, lane = tid & 63, wv = tid >> 6;
    __shared__ float xs[32][264];
    __shared__ float ws[96][36];

    int g = 0, oc0 = 0, ci = 0, kk = 0, ocb0 = 0;
    const float* wsrc;
    size_t wrow0;
    int wstride;
    if (!isbias) {
        g = bx >> 1; oc0 = (bx & 1) * 32;
        ci = g / 3; kk = g - ci * 3;
        wsrc = kw + (size_t)layer * KCL * 192;
        wrow0 = (size_t)((ci * 64 + oc0) * 3 + kk) * 192;
        wstride = 576;
    } else {
        ocb0 = (bx - 192) * 32;
        wsrc = bias_w;
        wrow0 = (size_t)ocb0 * 192;
        wstride = 192;
    }

    float acc[8][4];
#pragma unroll
    for (int oi = 0; oi < 8; ++oi) {
        float bv = isbias ? bias_b[ocb0 + wv * 8 + oi]
                          : kb[layer * KCL + (ci * 64 + oc0 + wv * 8 + oi) * 3 + kk];
#pragma unroll
        for (int si = 0; si < 4; ++si) acc[oi][si] = bv;
    }

    for (int half = 0; half < 2; ++half) {
        const int hc0 = half * 32;
        __syncthreads();
        for (int idx = tid; idx < 32 * 64; idx += 256) {
            int c = idx >> 6, q = idx & 63;
            *(float4*)&xs[c][4 + 4 * q] =
                *(const float4*)(kp_h + ((size_t)b * 64 + hc0 + c) * LL + 4 * q);
        }
        if (tid < 32) { xs[tid][3] = 0.f; xs[tid][260] = 0.f; }
        for (int idx = tid; idx < 3072; idx += 256) {
            int ocl = idx / 96, jj = idx - ocl * 96;
            ws[jj][ocl] = wsrc[wrow0 + (size_t)ocl * wstride + hc0 * 3 + jj];
        }
        __syncthreads();
        for (int c = 0; c < 32; ++c) {
#pragma unroll
            for (int t = 0; t < 3; ++t) {
                float wv8[8];
                *(float4*)&wv8[0] = *(const float4*)&ws[c * 3 + t][wv * 8];
                *(float4*)&wv8[4] = *(const float4*)&ws[c * 3 + t][wv * 8 + 4];
                float xv[4];
#pragma unroll
                for (int si = 0; si < 4; ++si) xv[si] = xs[c][lane + si * 64 + t + 3];
#pragma unroll
                for (int oi = 0; oi < 8; ++oi)
#pragma unroll
                    for (int si = 0; si < 4; ++si)
                        acc[oi][si] += wv8[oi] * xv[si];
            }
        }
    }

    if (!isbias) {
#pragma unroll
        for (int si = 0; si < 4; ++si) {
            int l = lane + si * 64;
            float* op = kh + ((size_t)b * LL + l) * KCL + g * 64 + oc0 + wv * 8;
            *(float4*)(op)     = make_float4(acc[0][si], acc[1][si], acc[2][si], acc[3][si]);
            *(float4*)(op + 4) = make_float4(acc[4][si], acc[5][si], acc[6][si], acc[7][si]);
        }
    } else {
#pragma unroll
        for (int oi = 0; oi < 8; ++oi) {
            float* op = bh + ((size_t)b * 256 + ocb0 + wv * 8 + oi) * LL;
#pragma unroll
            for (int si = 0; si < 4; ++si)
                op[lane + si * 64] = acc[oi][si];
        }
    }
}

// ---------------- fused dilated conv + LVC + gate + residual ----------------
// Phase A/B/C = round-0. Phase D restructured: wave owns a-chans wv*4..+3 AND
// their g-chans, all 256 cols (si=4) -> 2 uniform b128 + 4 b32 per (c,k),
// no weight-read duplication across waves. Same (c,k) accumulation order.
__global__ void __launch_bounds__(512, 4) layer_fused(
    const float* __restrict__ kh, const float* __restrict__ bh,
    const float* __restrict__ w, const float* __restrict__ bias,
    const float* __restrict__ hin, float* __restrict__ hout,
    int layer, int dil) {
    const int l = blockIdx.x, b = blockIdx.y;
    const int tid = threadIdx.x, lane = tid & 63, wv = tid >> 6;
    const int t0 = l * 256;
    __shared__ float xh[32][316];   // 40.4 KB
    __shared__ float ks[KCL];       // 24.6 KB
    __shared__ float ws[96][36];    // 13.8 KB

    const float* hb = hin + (size_t)b * 32 * T;
    for (int idx = tid; idx < 32 * 64; idx += 512) {
        int c = idx >> 6, q = idx & 63;
        float4 v = *(const float4*)(hb + (size_t)c * T + t0 + 4 * q);
        *(float4*)&xh[c][32 + 4 * q] = make_float4(lrelu_f(v.x), lrelu_f(v.y),
                                                   lrelu_f(v.z), lrelu_f(v.w));
    }
    for (int idx = tid; idx < 32 * 60; idx += 512) {
        int c = idx / 60, r = idx - c * 60;
        int jj = (r < 32) ? r : (256 + r);
        int t = t0 + jj - 32;
        xh[c][jj] = (t >= 0 && t < T) ? lrelu_f(hb[(size_t)c * T + t]) : 0.f;
    }
    {
        const float4* kp = (const float4*)(kh + ((size_t)b * LL + l) * KCL);
        float4* kd = (float4*)ks;
        for (int idx = tid; idx < KCL / 4; idx += 512) kd[idx] = kp[idx];
    }
    for (int idx = tid; idx < 3072; idx += 512) {
        int oc = idx / 96, ck = idx - oc * 96;
        ws[ck][oc] = w[oc * 96 + ck];
    }
    __syncthreads();

    // Phase B: dilated conv -> y regs. wave owns oc4 = wv*4; col = lane + si*64, col<258.
    const int oc4 = wv * 4;
    float yv[5][4];
    {
        float a[5][4];
#pragma unroll
        for (int oi = 0; oi < 4; ++oi) {
            float bv = bias[oc4 + oi];
#pragma unroll
            for (int si = 0; si < 5; ++si) a[si][oi] = bv;
        }
        for (int c = 0; c < 32; ++c) {
#pragma unroll
            for (int k = 0; k < 3; ++k) {
                float4 wq = *(const float4*)&ws[c * 3 + k][oc4];
                float xv[5];
#pragma unroll
                for (int si = 0; si < 5; ++si) {
                    int col = lane + si * 64;
                    int colc = (col < 258) ? col : 257;
                    xv[si] = xh[c][colc + 31 + (k - 1) * dil];
                }
#pragma unroll
                for (int si = 0; si < 5; ++si) {
                    a[si][0] += xv[si] * wq.x;
                    a[si][1] += xv[si] * wq.y;
                    a[si][2] += xv[si] * wq.z;
                    a[si][3] += xv[si] * wq.w;
                }
            }
        }
#pragma unroll
        for (int si = 0; si < 5; ++si) {
            int t = t0 - 1 + lane + si * 64;
            bool tval = (t >= 0 && t < T);
#pragma unroll
            for (int oi = 0; oi < 4; ++oi)
                yv[si][oi] = tval ? lrelu_f(a[si][oi]) : 0.f;
        }
    }
    __syncthreads();

    // Phase C: write y into xh central region
#pragma unroll
    for (int si = 0; si < 5; ++si) {
        int col = lane + si * 64;
        if (col < 258) {
#pragma unroll
            for (int oi = 0; oi < 4; ++oi) xh[oc4 + oi][col + 31] = yv[si][oi];
        }
    }
    __syncthreads();

    // Phase D: LVC. wave owns a-chans oc4..+3 and g-chans 32+oc4..+3, all 256 cols.
    float acc_a[4][4], acc_g[4][4];   // [oi][si]
#pragma unroll
    for (int oi = 0; oi < 4; ++oi) {
        float ba = bh[((size_t)b * 256 + layer * 64 + oc4 + oi) * LL + l];
        float bg = bh[((size_t)b * 256 + layer * 64 + 32 + oc4 + oi) * LL + l];
#pragma unroll
        for (int si = 0; si < 4; ++si) { acc_a[oi][si] = ba; acc_g[oi][si] = bg; }
    }

    for (int c = 0; c < 32; ++c) {
#pragma unroll
        for (int k = 0; k < 3; ++k) {
            const float* kr = ks + (c * 3 + k) * 64;
            float4 wa = *(const float4*)(kr + oc4);
            float4 wg = *(const float4*)(kr + 32 + oc4);
            float xv[4];
#pragma unroll
            for (int si = 0; si < 4; ++si)
                xv[si] = xh[c][lane + si * 64 + k + 31];
#pragma unroll
            for (int si = 0; si < 4; ++si) {
                acc_a[0][si] += wa.x * xv[si];
                acc_a[1][si] += wa.y * xv[si];
                acc_a[2][si] += wa.z * xv[si];
                acc_a[3][si] += wa.w * xv[si];
                acc_g[0][si] += wg.x * xv[si];
                acc_g[1][si] += wg.y * xv[si];
                acc_g[2][si] += wg.z * xv[si];
                acc_g[3][si] += wg.w * xv[si];
            }
        }
    }

    // Phase E: gate + residual
#pragma unroll
    for (int oi = 0; oi < 4; ++oi) {
        const float* hip = hin + ((size_t)b * 32 + oc4 + oi) * T + t0;
        float* hop = hout + ((size_t)b * 32 + oc4 + oi) * T + t0;
#pragma unroll
        for (int si = 0; si < 4; ++si) {
            int s = lane + si * 64;
            float a = acc_a[oi][si], g = acc_g[oi][si];
            float sg = 1.f / (1.f + __expf(-a));
            float th = tanhf(g);
            hop[s] = sg * th + hip[s];
        }
    }
}

extern "C" void kernel_launch(void* const* d_in, const int* in_sizes, int n_in,
                              void* d_out, int out_size, void* d_ws, size_t ws_size,
                              hipStream_t stream) {
    const float* hidden  = (const float*)d_in[0];
    const float* spec    = (const float*)d_in[1];
    const float* convt_w = (const float*)d_in[2];
    const float* convt_b = (const float*)d_in[3];
    const float* kp_in_w = (const float*)d_in[4];
    const float* kp_in_b = (const float*)d_in[5];
    const float* rb_w1   = (const float*)d_in[6];
    const float* rb_b1   = (const float*)d_in[7];
    const float* rb_w2   = (const float*)d_in[8];
    const float* rb_b2   = (const float*)d_in[9];
    const float* kern_w  = (const float*)d_in[10];
    const float* kern_b  = (const float*)d_in[11];
    const float* bias_w  = (const float*)d_in[12];
    const float* bias_b  = (const float*)d_in[13];
    const float* lvc_w   = (const float*)d_in[14];
    const float* lvc_b   = (const float*)d_in[15];

    float* wsp = (float*)d_ws;
    float* h_ws     = wsp;                                 // NB*32*T
    float* kh_layer = h_ws + (size_t)NB * 32 * T;          // NB*LL*KCL
    float* bh       = kh_layer + (size_t)NB * LL * KCL;    // NB*256*LL
    float* kp_h     = bh + (size_t)NB * 256 * LL;          // NB*64*LL
    float* trb      = kp_h + (size_t)NB * 64 * LL;         // 6*192*64 = 73728
    float* tkpin    = trb + (size_t)6 * 192 * 64;          // 500*64   = 32000

    float* h0 = (float*)d_out;
    float* h1 = h_ws;

    // 0) one-time weight transposes for trunk
    prep1<<<dim3(7), 256, 0, stream>>>(rb_w1, rb_w2, kp_in_w, trb, tkpin);

    // 1) merged trunk (blocks 0..127, scheduled first) + convt (blocks 128..391)
    phase1<<<dim3(392), 512, 0, stream>>>(hidden, convt_w, convt_b, h0,
                                          spec, tkpin, kp_in_b,
                                          trb, rb_b1, rb_b2, kp_h);

    static const int dil[4] = {1, 3, 9, 27};
    float* hin = h0;
    float* hout = h1;
    for (int layer = 0; layer < 4; ++layer) {
        kern_head<<<dim3(layer == 0 ? 200 : 192, NB), 256, 0, stream>>>(
            kp_h, kern_w, kern_b, bias_w, bias_b, kh_layer, bh, layer);
        layer_fused<<<dim3(LL, NB), 512, 0, stream>>>(
            kh_layer, bh, lvc_w + (size_t)layer * 32 * 32 * 3, lvc_b + layer * 32,
            hin, hout, layer, dil[layer]);
        float* tmp = hin; hin = hout; hout = tmp;
    }
    // after 4 swaps the final output landed in h0 = d_out
}

// Round 8
// 735.987 us; speedup vs baseline: 1.5815x; 1.0970x over previous
//
#include <hip/hip_runtime.h>
#include <math.h>

#define NB 4
#define T 65536
#define TIN 8192
#define LL 256
#define KCL 6144   // per-layer kernel channels = 32*64*3

__device__ __forceinline__ float lrelu_f(float v) { return v >= 0.f ? v : 0.2f * v; }

// ---------------- phase1: convt (264 blocks) + trunk (32 blocks) merged (R0, measured 112us) ----------------
union Phase1LDS {
    struct { float xs[32][264]; float wm[64][128]; } cvt;            // 65.8 KB
    struct { float hs[64][56]; float xsp[20][56]; float wt[192][68]; } trk; // 71.0 KB
};

__global__ void __launch_bounds__(512) phase1(
    const float* __restrict__ x, const float* __restrict__ cw,
    const float* __restrict__ cbias, float* __restrict__ hout,
    const float* __restrict__ spec,
    const float* __restrict__ kp_in_w, const float* __restrict__ kp_in_b,
    const float* __restrict__ rb_w1, const float* __restrict__ rb_b1,
    const float* __restrict__ rb_w2, const float* __restrict__ rb_b2,
    float* __restrict__ kp_h) {
    __shared__ Phase1LDS u;
    const int bid = blockIdx.x;
    const int tid = threadIdx.x;
    const int lane = tid & 63, wv = tid >> 6;

    if (bid < 264) {
        // ================= convt role =================
        const int bx = bid % 33;
        const int rr = bid / 33;
        const int mtp = rr & 1;
        const int b = rr >> 1;
        const int s0base = bx * 256;
        float (*xs)[264] = u.cvt.xs;
        float (*wm)[128] = u.cvt.wm;

        const float* xb = x + (size_t)b * 32 * TIN;
        for (int idx = tid; idx < 32 * 64; idx += 512) {
            int c = idx >> 6, q = idx & 63;
            int p = s0base + q * 4;
            float4 v = (p + 3 < TIN) ? *(const float4*)(xb + c * TIN + p)
                                     : make_float4(0.f, 0.f, 0.f, 0.f);
            *(float4*)&xs[c][4 + 4 * q] = v;
        }
        if (tid < 32) {
            int p = s0base - 1;
            xs[tid][3] = (p >= 0) ? xb[tid * TIN + p] : 0.f;
        }
        for (int idx = tid; idx < 8192; idx += 512) {
            int i = idx >> 7, mm = idx & 127;
            int oo = mtp * 16 + (mm >> 3), k0 = mm & 7;
            wm[i][mm] = (i < 32) ? cw[i * 512 + oo * 16 + k0]
                                 : cw[(i - 32) * 512 + oo * 16 + k0 + 8];
        }
        __syncthreads();

        float acc[2][8][4];   // [ol][k0][si]
#pragma unroll
        for (int ol = 0; ol < 2; ++ol) {
            float bo = cbias[mtp * 16 + wv * 2 + ol];
#pragma unroll
            for (int k0 = 0; k0 < 8; ++k0)
#pragma unroll
                for (int si = 0; si < 4; ++si) acc[ol][k0][si] = bo;
        }

        for (int c = 0; c < 32; ++c) {
            float xm1[4], x0[4];
#pragma unroll
            for (int si = 0; si < 4; ++si) {
                xm1[si] = xs[c][lane + si * 64 + 3];
                x0[si]  = xs[c][lane + si * 64 + 4];
            }
            float w0[16], w1[16];
#pragma unroll
            for (int q = 0; q < 4; ++q) {
                *(float4*)&w0[q * 4] = *(const float4*)&wm[c][wv * 16 + q * 4];
                *(float4*)&w1[q * 4] = *(const float4*)&wm[32 + c][wv * 16 + q * 4];
            }
#pragma unroll
            for (int ol = 0; ol < 2; ++ol)
#pragma unroll
                for (int k0 = 0; k0 < 8; ++k0)
#pragma unroll
                    for (int si = 0; si < 4; ++si)
                        acc[ol][k0][si] += x0[si] * w0[ol * 8 + k0] + xm1[si] * w1[ol * 8 + k0];
        }

#pragma unroll
        for (int ol = 0; ol < 2; ++ol) {
            float* ob = hout + ((size_t)b * 32 + mtp * 16 + wv * 2 + ol) * T;
#pragma unroll
            for (int si = 0; si < 4; ++si) {
                int tb = (s0base + lane + si * 64) * 8 - 4;
                if (tb >= 0 && tb < T)
                    *(float4*)(ob + tb) = make_float4(acc[ol][0][si], acc[ol][1][si],
                                                      acc[ol][2][si], acc[ol][3][si]);
                if (tb + 4 >= 0 && tb + 4 < T)
                    *(float4*)(ob + tb + 4) = make_float4(acc[ol][4][si], acc[ol][5][si],
                                                          acc[ol][6][si], acc[ol][7][si]);
            }
        }
        return;
    }

    // ================= trunk role =================
    const int tb = bid - 264;
    const int lq = tb & 7, b = tb >> 3;
    const int j = lane;
    const int oc0 = wv * 8;
    const int l0 = lq * 32;
    const int labs = l0 - 9 + j;
    const bool lvalid = (labs >= 0 && labs < 256);

    float (*hs)[56] = u.trk.hs;
    float (*xsp)[56] = u.trk.xsp;
    float (*wt)[68] = u.trk.wt;

    float pw[24];
    float px[3];

    auto pf_kpin = [&](int cc) {
#pragma unroll
        for (int t = 0; t < 13; ++t) {
            int idx = t * 512 + tid;
            pw[t] = 0.f;
            if (idx < 6400) pw[t] = kp_in_w[(size_t)(idx / 100) * 500 + cc * 100 + (idx % 100)];
        }
    };
    auto wr_kpin = [&]() {
#pragma unroll
        for (int t = 0; t < 13; ++t) {
            int idx = t * 512 + tid;
            if (idx < 6400) wt[idx % 100][idx / 100] = pw[t];
        }
    };
    auto pf_xsp = [&](int cc) {
#pragma unroll
        for (int t = 0; t < 3; ++t) {
            int idx = t * 512 + tid;
            px[t] = 0.f;
            if (idx < 1120) {
                int c = idx / 56, jj = idx - c * 56;
                int l = l0 - 9 + jj;
                if (l >= 0 && l < 256)
                    px[t] = spec[((size_t)b * 100 + cc * 20 + c) * LL + l];
            }
        }
    };
    auto wr_xsp = [&]() {
#pragma unroll
        for (int t = 0; t < 3; ++t) {
            int idx = t * 512 + tid;
            if (idx < 1120) xsp[idx / 56][idx % 56] = px[t];
        }
    };
    auto pf_w192 = [&](const float* src) {
#pragma unroll
        for (int t = 0; t < 24; ++t) pw[t] = src[t * 512 + tid];
    };
    auto wr_w192 = [&]() {
#pragma unroll
        for (int t = 0; t < 24; ++t) {
            int idx = t * 512 + tid;
            wt[idx % 192][idx / 192] = pw[t];
        }
    };
    auto conv64 = [&](int jlo, int jhi, const float* bptr, float* a) {
#pragma unroll
        for (int oi = 0; oi < 8; ++oi) a[oi] = bptr[oc0 + oi];
        if (j >= jlo && j < jhi) {
            for (int c = 0; c < 64; ++c) {
                float x0 = hs[c][j - 1], x1 = hs[c][j], x2 = hs[c][j + 1];
#pragma unroll
                for (int k = 0; k < 3; ++k) {
                    float xk = (k == 0) ? x0 : (k == 1) ? x1 : x2;
                    float w8[8];
                    *(float4*)&w8[0] = *(const float4*)&wt[c * 3 + k][oc0];
                    *(float4*)&w8[4] = *(const float4*)&wt[c * 3 + k][oc0 + 4];
#pragma unroll
                    for (int oi = 0; oi < 8; ++oi) a[oi] += xk * w8[oi];
                }
            }
        }
    };

    // ---- kp_in: 5 cc pages ----
    pf_kpin(0); pf_xsp(0);
    wr_kpin(); wr_xsp();
    __syncthreads();

    float acc[8];
#pragma unroll
    for (int oi = 0; oi < 8; ++oi) acc[oi] = kp_in_b[oc0 + oi];

    for (int cc = 0; cc < 5; ++cc) {
        if (cc < 4) { pf_kpin(cc + 1); pf_xsp(cc + 1); }
        else        { pf_w192(rb_w1); }
        if (j >= 2 && j < 48) {
            for (int c = 0; c < 20; ++c) {
                float x5[5];
#pragma unroll
                for (int u2 = 0; u2 < 5; ++u2) x5[u2] = xsp[c][j - 2 + u2];
#pragma unroll
                for (int k = 0; k < 5; ++k) {
                    float w8[8];
                    *(float4*)&w8[0] = *(const float4*)&wt[c * 5 + k][oc0];
                    *(float4*)&w8[4] = *(const float4*)&wt[c * 5 + k][oc0 + 4];
#pragma unroll
                    for (int oi = 0; oi < 8; ++oi) acc[oi] += x5[k] * w8[oi];
                }
            }
        }
        if (cc == 4 && j >= 2 && j < 48) {
#pragma unroll
            for (int oi = 0; oi < 8; ++oi) hs[oc0 + oi][j] = lvalid ? acc[oi] : 0.f;
        }
        __syncthreads();
        if (cc < 4) { wr_kpin(); wr_xsp(); }
        else        { wr_w192(); }
        __syncthreads();
    }

    // ---- 3 residual blocks ----
    for (int i = 0; i < 3; ++i) {
        const int jlo1 = 3 + 2 * i, jhi1 = 47 - 2 * i;
        const int jlo2 = jlo1 + 1, jhi2 = jhi1 - 1;
        float r[8];
        if (j >= jlo2 && j < jhi2) {
#pragma unroll
            for (int oi = 0; oi < 8; ++oi) r[oi] = hs[oc0 + oi][j];
        }
        // conv1
        pf_w192(rb_w2 + (size_t)i * 12288);
        float a1[8];
        conv64(jlo1, jhi1, rb_b1 + i * 64, a1);
        __syncthreads();
        if (j >= jlo1 && j < jhi1) {
#pragma unroll
            for (int oi = 0; oi < 8; ++oi) hs[oc0 + oi][j] = lvalid ? lrelu_f(a1[oi]) : 0.f;
        }
        wr_w192();
        __syncthreads();
        // conv2
        if (i < 2) pf_w192(rb_w1 + (size_t)(i + 1) * 12288);
        float a2[8];
        conv64(jlo2, jhi2, rb_b2 + i * 64, a2);
        __syncthreads();
        if (j >= jlo2 && j < jhi2) {
#pragma unroll
            for (int oi = 0; oi < 8; ++oi) hs[oc0 + oi][j] = lvalid ? (lrelu_f(a2[oi]) + r[oi]) : 0.f;
        }
        if (i < 2) wr_w192();
        __syncthreads();
    }

    // ---- write kp_h (central 32 cols) ----
    for (int idx = tid; idx < 64 * 32; idx += 512) {
        int c = idx >> 5, jj = idx & 31;
        kp_h[((size_t)b * 64 + c) * LL + l0 + jj] = hs[c][9 + jj];
    }
}

// ---------------- kern head core: 512 threads, 8 waves x 4 oc (same accumulation order as R0) ----------------
__device__ __forceinline__ void khead_core(
    int bx, int b, int tid,
    const float* __restrict__ kp_h, const float* __restrict__ kw,
    const float* __restrict__ kb, const float* __restrict__ bias_w,
    const float* __restrict__ bias_b, float* __restrict__ kh,
    float* __restrict__ bh, int layer,
    float (*xs)[264], float (*ws)[36]) {
    const bool isbias = (bx >= 192);
    const int lane = tid & 63, wv = tid >> 6;   // wv 0..7
    int g = 0, oc0 = 0, ci = 0, kk = 0, ocb0 = 0;
    const float* wsrc;
    size_t wrow0;
    int wstride;
    if (!isbias) {
        g = bx >> 1; oc0 = (bx & 1) * 32;
        ci = g / 3; kk = g - ci * 3;
        wsrc = kw + (size_t)layer * KCL * 192;
        wrow0 = (size_t)((ci * 64 + oc0) * 3 + kk) * 192;
        wstride = 576;
    } else {
        ocb0 = (bx - 192) * 32;
        wsrc = bias_w;
        wrow0 = (size_t)ocb0 * 192;
        wstride = 192;
    }
    const int oc4w = wv * 4;

    float acc[4][4];
#pragma unroll
    for (int oi = 0; oi < 4; ++oi) {
        float bv = isbias ? bias_b[ocb0 + oc4w + oi]
                          : kb[layer * KCL + (ci * 64 + oc0 + oc4w + oi) * 3 + kk];
#pragma unroll
        for (int si = 0; si < 4; ++si) acc[oi][si] = bv;
    }

    for (int half = 0; half < 2; ++half) {
        const int hc0 = half * 32;
        __syncthreads();
        for (int idx = tid; idx < 32 * 64; idx += 512) {
            int c = idx >> 6, q = idx & 63;
            *(float4*)&xs[c][4 + 4 * q] =
                *(const float4*)(kp_h + ((size_t)b * 64 + hc0 + c) * LL + 4 * q);
        }
        if (tid < 32) { xs[tid][3] = 0.f; xs[tid][260] = 0.f; }
        for (int idx = tid; idx < 3072; idx += 512) {
            int ocl = idx / 96, jj = idx - ocl * 96;
            ws[jj][ocl] = wsrc[wrow0 + (size_t)ocl * wstride + hc0 * 3 + jj];
        }
        __syncthreads();
        for (int c = 0; c < 32; ++c) {
#pragma unroll
            for (int t = 0; t < 3; ++t) {
                float4 w4 = *(const float4*)&ws[c * 3 + t][oc4w];
                float xv[4];
#pragma unroll
                for (int si = 0; si < 4; ++si) xv[si] = xs[c][lane + si * 64 + t + 3];
#pragma unroll
                for (int si = 0; si < 4; ++si) {
                    acc[0][si] += w4.x * xv[si];
                    acc[1][si] += w4.y * xv[si];
                    acc[2][si] += w4.z * xv[si];
                    acc[3][si] += w4.w * xv[si];
                }
            }
        }
    }

    if (!isbias) {
#pragma unroll
        for (int si = 0; si < 4; ++si) {
            int l = lane + si * 64;
            float* op = kh + ((size_t)b * LL + l) * KCL + g * 64 + oc0 + oc4w;
            *(float4*)op = make_float4(acc[0][si], acc[1][si], acc[2][si], acc[3][si]);
        }
    } else {
#pragma unroll
        for (int oi = 0; oi < 4; ++oi) {
            float* op = bh + ((size_t)b * 256 + ocb0 + oc4w + oi) * LL;
#pragma unroll
            for (int si = 0; si < 4; ++si)
                op[lane + si * 64] = acc[oi][si];
        }
    }
}

__global__ void __launch_bounds__(512, 2) kern_head512(
    const float* __restrict__ kp_h, const float* __restrict__ kw,
    const float* __restrict__ kb, const float* __restrict__ bias_w,
    const float* __restrict__ bias_b, float* __restrict__ kh,
    float* __restrict__ bh, int layer) {
    __shared__ float xs[32][264];
    __shared__ float ws[96][36];
    khead_core(blockIdx.x, blockIdx.y, threadIdx.x, kp_h, kw, kb, bias_w, bias_b,
               kh, bh, layer, xs, ws);
}

// ---------------- layer_fused core (R0 verbatim) ----------------
__device__ __forceinline__ void lf_core(
    int l, int b, int tid,
    const float* __restrict__ kh, const float* __restrict__ bh,
    const float* __restrict__ w, const float* __restrict__ bias,
    const float* __restrict__ hin, float* __restrict__ hout,
    int layer, int dil,
    float (*xh)[316], float* ks, float (*ws)[36]) {
    const int lane = tid & 63, wv = tid >> 6;
    const int t0 = l * 256;

    const float* hb = hin + (size_t)b * 32 * T;
    for (int idx = tid; idx < 32 * 64; idx += 512) {
        int c = idx >> 6, q = idx & 63;
        float4 v = *(const float4*)(hb + (size_t)c * T + t0 + 4 * q);
        *(float4*)&xh[c][32 + 4 * q] = make_float4(lrelu_f(v.x), lrelu_f(v.y),
                                                   lrelu_f(v.z), lrelu_f(v.w));
    }
    for (int idx = tid; idx < 32 * 60; idx += 512) {
        int c = idx / 60, r = idx - c * 60;
        int jj = (r < 32) ? r : (256 + r);
        int t = t0 + jj - 32;
        xh[c][jj] = (t >= 0 && t < T) ? lrelu_f(hb[(size_t)c * T + t]) : 0.f;
    }
    {
        const float4* kp = (const float4*)(kh + ((size_t)b * LL + l) * KCL);
        float4* kd = (float4*)ks;
        for (int idx = tid; idx < KCL / 4; idx += 512) kd[idx] = kp[idx];
    }
    for (int idx = tid; idx < 3072; idx += 512) {
        int oc = idx / 96, ck = idx - oc * 96;
        ws[ck][oc] = w[oc * 96 + ck];
    }
    __syncthreads();

    // Phase B
    const int oc4 = wv * 4;
    float yv[5][4];
    {
        float a[5][4];
#pragma unroll
        for (int oi = 0; oi < 4; ++oi) {
            float bv = bias[oc4 + oi];
#pragma unroll
            for (int si = 0; si < 5; ++si) a[si][oi] = bv;
        }
        for (int c = 0; c < 32; ++c) {
#pragma unroll
            for (int k = 0; k < 3; ++k) {
                float4 wq = *(const float4*)&ws[c * 3 + k][oc4];
                float xv[5];
#pragma unroll
                for (int si = 0; si < 5; ++si) {
                    int col = lane + si * 64;
                    int colc = (col < 258) ? col : 257;
                    xv[si] = xh[c][colc + 31 + (k - 1) * dil];
                }
#pragma unroll
                for (int si = 0; si < 5; ++si) {
                    a[si][0] += xv[si] * wq.x;
                    a[si][1] += xv[si] * wq.y;
                    a[si][2] += xv[si] * wq.z;
                    a[si][3] += xv[si] * wq.w;
                }
            }
        }
#pragma unroll
        for (int si = 0; si < 5; ++si) {
            int t = t0 - 1 + lane + si * 64;
            bool tval = (t >= 0 && t < T);
#pragma unroll
            for (int oi = 0; oi < 4; ++oi)
                yv[si][oi] = tval ? lrelu_f(a[si][oi]) : 0.f;
        }
    }
    __syncthreads();

    // Phase C
#pragma unroll
    for (int si = 0; si < 5; ++si) {
        int col = lane + si * 64;
        if (col < 258) {
#pragma unroll
            for (int oi = 0; oi < 4; ++oi) xh[oc4 + oi][col + 31] = yv[si][oi];
        }
    }
    __syncthreads();

    // Phase D
    const int oc8 = (wv & 3) * 8;
    const int sh  = wv >> 2;
    float acc_a[8][2], acc_g[8][2];
#pragma unroll
    for (int oi = 0; oi < 8; ++oi) {
        float ba = bh[((size_t)b * 256 + layer * 64 + oc8 + oi) * LL + l];
        float bg = bh[((size_t)b * 256 + layer * 64 + 32 + oc8 + oi) * LL + l];
#pragma unroll
        for (int si = 0; si < 2; ++si) { acc_a[oi][si] = ba; acc_g[oi][si] = bg; }
    }

    for (int c = 0; c < 32; ++c) {
#pragma unroll
        for (int k = 0; k < 3; ++k) {
            const float* kr = ks + (c * 3 + k) * 64;
            float wa[8], wg[8];
            *(float4*)&wa[0] = *(const float4*)(kr + oc8);
            *(float4*)&wa[4] = *(const float4*)(kr + oc8 + 4);
            *(float4*)&wg[0] = *(const float4*)(kr + 32 + oc8);
            *(float4*)&wg[4] = *(const float4*)(kr + 32 + oc8 + 4);
            float xv2[2];
#pragma unroll
            for (int si = 0; si < 2; ++si) {
                int s = lane + (sh * 2 + si) * 64;
                xv2[si] = xh[c][s + k + 31];
            }
#pragma unroll
            for (int oi = 0; oi < 8; ++oi)
#pragma unroll
                for (int si = 0; si < 2; ++si) {
                    acc_a[oi][si] += wa[oi] * xv2[si];
                    acc_g[oi][si] += wg[oi] * xv2[si];
                }
        }
    }

    // Phase E
#pragma unroll
    for (int oi = 0; oi < 8; ++oi) {
        const float* hip = hin + ((size_t)b * 32 + oc8 + oi) * T + t0;
        float* hop = hout + ((size_t)b * 32 + oc8 + oi) * T + t0;
#pragma unroll
        for (int si = 0; si < 2; ++si) {
            int s = lane + (sh * 2 + si) * 64;
            float a = acc_a[oi][si], g = acc_g[oi][si];
            float sg = 1.f / (1.f + __expf(-a));
            float th = tanhf(g);
            hop[s] = sg * th + hip[s];
        }
    }
}

// ---------------- fused: LF(layer) blocks + KH(layer+1) blocks in one dispatch ----------------
// kh_on=1: grid = 1792 = 7*256; role by bid%7 (3 KH : 4 LF), bijective.
// kh_on=0: grid = 1024, all LF.
union FusedLDS {
    struct { float xh[32][316]; float ks[KCL]; float ws[96][36]; } lf;  // 77 KB
    struct { float xs[32][264]; float ws[96][36]; } kh;                 // 47.6 KB
};

__global__ void __launch_bounds__(512, 2) fused(
    const float* __restrict__ kp_h, const float* __restrict__ kw,
    const float* __restrict__ kb, const float* __restrict__ bias_w,
    const float* __restrict__ bias_b,
    const float* __restrict__ kh_rd, float* __restrict__ kh_wr,
    float* __restrict__ bh,
    const float* __restrict__ lvcw, const float* __restrict__ lvcb,
    const float* __restrict__ hin, float* __restrict__ hout,
    int lf_layer, int dil, int kh_on) {
    __shared__ FusedLDS u;
    const int g = blockIdx.x;
    const int tid = threadIdx.x;
    if (kh_on) {
        const int r = g % 7, q7 = g / 7;
        if (r < 3) {
            const int ukh = q7 * 3 + r;          // 0..767
            const int bx = ukh % 192, b = ukh / 192;
            khead_core(bx, b, tid, kp_h, kw, kb, bias_w, bias_b,
                       kh_wr, bh, lf_layer + 1, u.kh.xs, u.kh.ws);
            return;
        }
        const int ulf = q7 * 4 + (r - 3);        // 0..1023
        lf_core(ulf & 255, ulf >> 8, tid, kh_rd, bh, lvcw, lvcb,
                hin, hout, lf_layer, dil, u.lf.xh, u.lf.ks, u.lf.ws);
    } else {
        lf_core(g & 255, g >> 8, tid, kh_rd, bh, lvcw, lvcb,
                hin, hout, lf_layer, dil, u.lf.xh, u.lf.ks, u.lf.ws);
    }
}

extern "C" void kernel_launch(void* const* d_in, const int* in_sizes, int n_in,
                              void* d_out, int out_size, void* d_ws, size_t ws_size,
                              hipStream_t stream) {
    const float* hidden  = (const float*)d_in[0];
    const float* spec    = (const float*)d_in[1];
    const float* convt_w = (const float*)d_in[2];
    const float* convt_b = (const float*)d_in[3];
    const float* kp_in_w = (const float*)d_in[4];
    const float* kp_in_b = (const float*)d_in[5];
    const float* rb_w1   = (const float*)d_in[6];
    const float* rb_b1   = (const float*)d_in[7];
    const float* rb_w2   = (const float*)d_in[8];
    const float* rb_b2   = (const float*)d_in[9];
    const float* kern_w  = (const float*)d_in[10];
    const float* kern_b  = (const float*)d_in[11];
    const float* bias_w  = (const float*)d_in[12];
    const float* bias_b  = (const float*)d_in[13];
    const float* lvc_w   = (const float*)d_in[14];
    const float* lvc_b   = (const float*)d_in[15];

    const size_t NH  = (size_t)NB * 32 * T;     // 8,388,608
    const size_t NKH = (size_t)NB * LL * KCL;   // 6,291,456
    const size_t NBH = (size_t)NB * 256 * LL;   //   262,144
    const size_t NKP = (size_t)NB * 64 * LL;    //    65,536
    const size_t need_pp = (NH + 2 * NKH + NBH + NKP) * sizeof(float);  // ~85.2 MB
    const bool pp = ws_size >= need_pp;

    float* wsp  = (float*)d_ws;
    float* h_ws = wsp;
    float* kh0  = h_ws + NH;
    float* kh1  = pp ? (kh0 + NKH) : kh0;
    float* bh   = (pp ? kh1 : kh0) + NKH;
    float* kp_h = bh + NBH;

    float* h0 = (float*)d_out;
    float* h1 = h_ws;

    // 1) merged convt + trunk (R0)
    phase1<<<dim3(296), 512, 0, stream>>>(hidden, convt_w, convt_b, h0,
                                          spec, kp_in_w, kp_in_b,
                                          rb_w1, rb_b1, rb_w2, rb_b2, kp_h);

    // 2) kern head layer 0 (incl. bias blocks)
    kern_head512<<<dim3(200, NB), 512, 0, stream>>>(
        kp_h, kern_w, kern_b, bias_w, bias_b, kh0, bh, 0);

    static const int dil[4] = {1, 3, 9, 27};
    float* hin = h0;
    float* hout = h1;
    for (int l = 0; l < 4; ++l) {
        const float* rd = (l & 1) ? kh1 : kh0;
        float* wr = (l & 1) ? kh0 : kh1;
        if (pp && l < 3) {
            fused<<<dim3(1792), 512, 0, stream>>>(
                kp_h, kern_w, kern_b, bias_w, bias_b, rd, wr, bh,
                lvc_w + (size_t)l * 32 * 32 * 3, lvc_b + l * 32,
                hin, hout, l, dil[l], 1);
        } else {
            fused<<<dim3(1024), 512, 0, stream>>>(
                kp_h, kern_w, kern_b, bias_w, bias_b, rd, (float*)rd, bh,
                lvc_w + (size_t)l * 32 * 32 * 3, lvc_b + l * 32,
                hin, hout, l, dil[l], 0);
            if (!pp && l < 3)
                kern_head512<<<dim3(192, NB), 512, 0, stream>>>(
                    kp_h, kern_w, kern_b, bias_w, bias_b, kh0, bh, l + 1);
        }
        float* tmp = hin; hin = hout; hout = tmp;
    }
    // after 4 swaps the final output landed in h0 = d_out
}